// Round 13
// baseline (164.109 us; speedup 1.0000x reference)
//
#include <hip/hip_runtime.h>
#include <hip/hip_bf16.h>
#include <math.h>

#define D      256
#define N2     8192
#define NHALF  4096
#define TILE   128
#define BK     64
#define NCH    4        // 256 / BK
#define LDW    68       // 136B row stride: read banks 2*row+16ks+4quad (r5-verified free); write banks 2r+8q -> 16 distinct
#define NBLK2  4096     // 64x64 tiles, one per block
#define TPB    512      // 8 waves/block, 2 blocks/CU -> 4 waves/SIMD (r12-verified)

typedef __bf16 bf16x8_t __attribute__((ext_vector_type(8)));
typedef float  f32x4_t  __attribute__((ext_vector_type(4)));

// ---------------- single fused kernel: stage(raw f32)+norm-in-epilogue sim + fin ----
// r12 ledger: total 122.4 = sim 69.7 + prep ~5 + ~47 fixed (≈15us/launch + ~30 base).
// This round removes the prep launch entirely: each block stages its two panels from
// the RAW fp32 inputs as UNNORMALIZED bf16 (bf16 relative error is scale-invariant),
// accumulates per-row sum-of-squares during staging, and applies 1/(|a_r||b_c|) as
// two mults in the epilogue before exp2. Positives = the sub-block diagonal of acc in
// blocks with bj==bi+32 (sim[k][k+N]), scaled and stored agent-scope. Inner loop is
// byte-identical to r12's verified core. Staging write map fixed to q*16 units:
// write bank = 2r+8q = 16 distinct per quarter-group (r12's u*8 map was 2-way,
// 4.19M conflict cycles). g_denom+tickets zeroed via one capturable hipMemsetAsync.
__global__ __launch_bounds__(TPB, 4) void fused_kernel(
        const float* __restrict__ a, const float* __restrict__ b,
        float* __restrict__ g_denom, float* __restrict__ g_pos,
        unsigned* __restrict__ g_t1, float* __restrict__ out) {
    __shared__ __bf16 ldsA[2][TILE * LDW];
    __shared__ __bf16 ldsB[2][TILE * LDW];
    __shared__ float  rnA[TILE], rnB[TILE];
    __shared__ float  sw[8];
    __shared__ bool   amLast;

    const int tid    = threadIdx.x;
    const int l      = tid & 63;
    const int lane15 = l & 15;
    const int quad   = l >> 4;
    const int w      = tid >> 6;               // wave 0..7
    const int wr     = (w & 3) * 32;           // wave rows: 32
    const int wc     = (w >> 2) * 64;          // wave cols: 64

    const int bi = blockIdx.x >> 6;            // row panel [0,64)
    const int bj = blockIdx.x & 63;            // col panel [0,64)

    // panel base in the raw inputs: global row g -> (g<4096 ? emb_i[g] : emb_j[g-4096])
    const float* pa = (bi < 32) ? (a + (size_t)bi * TILE * D)
                                : (b + (size_t)(bi - 32) * TILE * D);
    const float* pb = (bj < 32) ? (a + (size_t)bj * TILE * D)
                                : (b + (size_t)(bj - 32) * TILE * D);

    // staging map: thread t -> row r = t>>2, q = t&3 -> 16 f32 at k0+q*16
    const int r = tid >> 2;
    const int q = tid & 3;
    const float* gar = pa + (size_t)r * D + q * 16;
    const float* gbr = pb + (size_t)r * D + q * 16;
    const int wofs = r * LDW + q * 16;

    float ssa = 0.f, ssb = 0.f;                // per-thread sumsq partials (16 f32/chunk)
    f32x4_t va[4], vb[4];
    auto load_regs = [&](int c) {
        const float* A0 = gar + c * BK;
        const float* B0 = gbr + c * BK;
        #pragma unroll
        for (int u = 0; u < 4; ++u) {
            va[u] = *(const f32x4_t*)(A0 + u * 4);
            vb[u] = *(const f32x4_t*)(B0 + u * 4);
        }
    };
    auto write_lds = [&](int buf) {
        bf16x8_t oa0, oa1, ob0, ob1;
        #pragma unroll
        for (int e = 0; e < 4; ++e) {
            oa0[e]     = (__bf16)va[0][e]; oa0[e + 4] = (__bf16)va[1][e];
            oa1[e]     = (__bf16)va[2][e]; oa1[e + 4] = (__bf16)va[3][e];
            ob0[e]     = (__bf16)vb[0][e]; ob0[e + 4] = (__bf16)vb[1][e];
            ob1[e]     = (__bf16)vb[2][e]; ob1[e + 4] = (__bf16)vb[3][e];
            ssa += va[0][e]*va[0][e] + va[1][e]*va[1][e] + va[2][e]*va[2][e] + va[3][e]*va[3][e];
            ssb += vb[0][e]*vb[0][e] + vb[1][e]*vb[1][e] + vb[2][e]*vb[2][e] + vb[3][e]*vb[3][e];
        }
        *(bf16x8_t*)(&ldsA[buf][wofs])     = oa0;
        *(bf16x8_t*)(&ldsA[buf][wofs + 8]) = oa1;
        *(bf16x8_t*)(&ldsB[buf][wofs])     = ob0;
        *(bf16x8_t*)(&ldsB[buf][wofs + 8]) = ob1;
    };

    f32x4_t acc[2][4];
    #pragma unroll
    for (int mi = 0; mi < 2; ++mi)
        #pragma unroll
        for (int nj = 0; nj < 4; ++nj)
            acc[mi][nj] = (f32x4_t){0.f, 0.f, 0.f, 0.f};

    auto compute = [&](int buf) {
        #pragma unroll
        for (int ks = 0; ks < 2; ++ks) {
            bf16x8_t af[2], bff[4];
            #pragma unroll
            for (int mi = 0; mi < 2; ++mi)
                af[mi] = *(const bf16x8_t*)(&ldsA[buf][(wr + mi * 16 + lane15) * LDW + ks * 32 + quad * 8]);
            #pragma unroll
            for (int nj = 0; nj < 4; ++nj)
                bff[nj] = *(const bf16x8_t*)(&ldsB[buf][(wc + nj * 16 + lane15) * LDW + ks * 32 + quad * 8]);
            #pragma unroll
            for (int mi = 0; mi < 2; ++mi)
                #pragma unroll
                for (int nj = 0; nj < 4; ++nj)
                    acc[mi][nj] = __builtin_amdgcn_mfma_f32_16x16x32_bf16(bff[nj], af[mi], acc[mi][nj], 0, 0, 0);
        }
    };

    // prologue: stage chunk 0
    load_regs(0);
    write_lds(0);
    __syncthreads();

    int cur = 0;
    #pragma unroll
    for (int c = 0; c < NCH; ++c) {
        if (c + 1 < NCH) load_regs(c + 1);
        compute(cur);
        if (c + 1 < NCH) {
            write_lds(cur ^ 1);     // safe: buf[cur^1] readers all passed prior barrier
            __syncthreads();
            cur ^= 1;
        }
    }

    // row norms: 4 threads/row -> shuffle-reduce -> rnorm in LDS (needed in epilogue only)
    ssa += __shfl_xor(ssa, 1, 64); ssa += __shfl_xor(ssa, 2, 64);
    ssb += __shfl_xor(ssb, 1, 64); ssb += __shfl_xor(ssb, 2, 64);
    if (q == 0) {
        rnA[r] = 1.0f / fmaxf(sqrtf(ssa), 1e-8f);
        rnB[r] = 1.0f / fmaxf(sqrtf(ssb), 1e-8f);
    }
    __syncthreads();

    // epilogue: sim = acc*rsA*rsB; e = exp2(sim * (1/T)/ln2); zero self-diag;
    // positives from the bj==bi+32 sub-diagonal; register row sums.
    float rsA[2], rsB4[4][4];
    #pragma unroll
    for (int mi = 0; mi < 2; ++mi) rsA[mi] = rnA[wr + mi * 16 + lane15];
    #pragma unroll
    for (int nj = 0; nj < 4; ++nj)
        #pragma unroll
        for (int t = 0; t < 4; ++t) rsB4[nj][t] = rnB[wc + nj * 16 + quad * 4 + t];

    const bool posBlk = (bj == bi + 32);
    float rs[2] = {0.f, 0.f};
    #pragma unroll
    for (int mi = 0; mi < 2; ++mi) {
        #pragma unroll
        for (int nj = 0; nj < 4; ++nj) {
            const bool dg = (wr + mi * 16 == wc + nj * 16);   // wave-uniform
            #pragma unroll
            for (int t = 0; t < 4; ++t) {
                const float s = acc[mi][nj][t] * rsA[mi] * rsB4[nj][t];
                float e = exp2f(s * 2.8853900817779268f);
                if (dg && (quad * 4 + t) == lane15) {
                    if (bi == bj) e = 0.0f;                    // self-similarity
                    if (posBlk)                                 // sim[k][k+N] = positive
                        __hip_atomic_store(&g_pos[bi * TILE + wr + mi * 16 + lane15], s,
                                           __ATOMIC_RELAXED, __HIP_MEMORY_SCOPE_AGENT);
                }
                rs[mi] += e;
            }
        }
    }
    #pragma unroll
    for (int mi = 0; mi < 2; ++mi) {
        rs[mi] += __shfl_xor(rs[mi], 16, 64);
        rs[mi] += __shfl_xor(rs[mi], 32, 64);
    }
    if (l < 16) {
        #pragma unroll
        for (int mi = 0; mi < 2; ++mi)
            atomicAdd(&g_denom[bi * TILE + wr + mi * 16 + l], rs[mi]);
    }

    // ---------------- two-level fenceless ticket fin (r12-verified) ----------------
    __syncthreads();                 // drains vmcnt for every wave -> adds/stores done
    if (tid == 0) {
        asm volatile("s_waitcnt vmcnt(0)" ::: "memory");
        unsigned t1 = __hip_atomic_fetch_add(&g_t1[bi * 32], 1u, __ATOMIC_RELAXED,
                                             __HIP_MEMORY_SCOPE_AGENT);
        bool grpLast = (t1 == 63);
        unsigned t2 = 0;
        if (grpLast)
            t2 = __hip_atomic_fetch_add(&g_t1[64 * 32], 1u, __ATOMIC_RELAXED,
                                        __HIP_MEMORY_SCOPE_AGENT);
        amLast = grpLast && (t2 == 63);
    }
    __syncthreads();
    if (!amLast) return;

    // loss = [ sum_k log(denom_k) - 4 * sum_{w<N} pos_w ] / 2N
    float local = 0.0f;
    for (int k = tid; k < N2; k += TPB) {
        float dn = __hip_atomic_load(&g_denom[k], __ATOMIC_RELAXED,
                                     __HIP_MEMORY_SCOPE_AGENT);
        local += logf(dn);
        if (k < NHALF) {
            float p = __hip_atomic_load(&g_pos[k], __ATOMIC_RELAXED,
                                        __HIP_MEMORY_SCOPE_AGENT);
            local -= 4.0f * p;
        }
    }
    #pragma unroll
    for (int off = 32; off; off >>= 1) local += __shfl_xor(local, off, 64);
    if (l == 0) sw[w] = local;
    __syncthreads();
    if (tid == 0) {
        float s = 0.f;
        #pragma unroll
        for (int i = 0; i < 8; ++i) s += sw[i];
        out[0] = s / (float)N2;
    }
}

extern "C" void kernel_launch(void* const* d_in, const int* in_sizes, int n_in,
                              void* d_out, int out_size, void* d_ws, size_t ws_size,
                              hipStream_t stream) {
    const float* emb_i = (const float*)d_in[0];
    const float* emb_j = (const float*)d_in[1];

    float*    g_denom = (float*)d_ws;                       // 8192 f32
    unsigned* g_t1    = (unsigned*)(g_denom + N2);          // 64*32+1 tickets (+pad)
    float*    g_pos   = (float*)(g_t1 + 64 * 32 + 8);       // 4096 f32 (no zero needed)
    float*    out     = (float*)d_out;

    // zero denom + tickets (graph-capturable memset node; harness uses the same op)
    hipMemsetAsync(d_ws, 0, (size_t)N2 * 4 + (64 * 32 + 8) * 4, stream);
    fused_kernel<<<NBLK2, TPB, 0, stream>>>(emb_i, emb_j, g_denom, g_pos, g_t1, out);
}

// Round 14
// 122.312 us; speedup vs baseline: 1.3417x; 1.3417x over previous
//
#include <hip/hip_runtime.h>
#include <hip/hip_bf16.h>
#include <math.h>

#define D      256
#define N2     8192
#define NHALF  4096
#define TILE   128
#define BK     64
#define NCH    4        // 256 / BK
#define LDW    68       // 136B row stride: read map r5/r12-verified conflict-free
#define NBLK2  4096     // 64x64 tiles, one per block
#define TPB    512      // 8 waves/block, 2 blocks/CU -> 4 waves/SIMD (r12-verified)

typedef __bf16 bf16x8_t __attribute__((ext_vector_type(8)));
typedef __bf16 bf16x4_t __attribute__((ext_vector_type(4)));
typedef float  f32x4_t  __attribute__((ext_vector_type(4)));

// ---------------- kernel 1: fused normalize + positives + denom/ticket zero --------
__global__ __launch_bounds__(256) void prep_kernel(const float* __restrict__ a,
                                                   const float* __restrict__ b,
                                                   __bf16* __restrict__ zb,
                                                   float* __restrict__ g_pos,
                                                   float* __restrict__ g_denom,
                                                   unsigned* __restrict__ g_t1) {
    const int tid = threadIdx.x;
    const int gt  = blockIdx.x * 256 + tid;
    if (gt < N2) g_denom[gt] = 0.0f;
    if (gt < 64 * 32 + 1) g_t1[gt] = 0u;       // 64 spaced L1 tickets + 1 L2 ticket

    const int w = blockIdx.x * 4 + (tid >> 6);  // pair row in [0, NHALF)
    const int l = tid & 63;
    float4 x = ((const float4*)(a + (size_t)w * D))[l];
    float4 y = ((const float4*)(b + (size_t)w * D))[l];
    float sxx = x.x * x.x + x.y * x.y + x.z * x.z + x.w * x.w;
    float syy = y.x * y.x + y.y * y.y + y.z * y.z + y.w * y.w;
    float sxy = x.x * y.x + x.y * y.y + x.z * y.z + x.w * y.w;
    #pragma unroll
    for (int off = 32; off; off >>= 1) {
        sxx += __shfl_xor(sxx, off, 64);
        syy += __shfl_xor(syy, off, 64);
        sxy += __shfl_xor(sxy, off, 64);
    }
    const float rx = 1.0f / fmaxf(sqrtf(sxx), 1e-8f);
    const float ry = 1.0f / fmaxf(sqrtf(syy), 1e-8f);

    bf16x4_t ox, oy;
    ox[0] = (__bf16)(x.x * rx); ox[1] = (__bf16)(x.y * rx);
    ox[2] = (__bf16)(x.z * rx); ox[3] = (__bf16)(x.w * rx);
    oy[0] = (__bf16)(y.x * ry); oy[1] = (__bf16)(y.y * ry);
    oy[2] = (__bf16)(y.z * ry); oy[3] = (__bf16)(y.w * ry);
    *(bf16x4_t*)(zb + (size_t)w * D + l * 4)           = ox;
    *(bf16x4_t*)(zb + (size_t)(w + NHALF) * D + l * 4) = oy;

    if (l == 0) {
        const float p = sxy * rx * ry;
        g_pos[w]         = p;
        g_pos[w + NHALF] = p;
    }
}

// ---------------- kernel 2: r12 sim + r13's verified 0-conflict staging map --------
// r13 post-mortem: fusing prep (f32 staging + in-loop cvt) cost +55us of kernel for
// ~10us of launch savings (FETCH 2x, VALU cvt in the barrier-locked phase, scratch
// spill WRITE 45MB). Reverted to r12 (122.4us best). Single change vs r12: the
// staging WRITE map. r12's (u*8, u*8+32) measured 4.19M LDS conflict cycles; r13's
// (q*16, q*16+8) measured 0 on identical hardware phases. Same bytes, same verified
// read path (r5/r12: 0 read conflicts). Empirical bank truth > hand models (twice
// wrong). Everything else byte-identical to r12.
__global__ __launch_bounds__(TPB, 4) void sim_kernel(const __bf16* __restrict__ zb,
                                                     float* __restrict__ g_denom,
                                                     const float* __restrict__ g_pos,
                                                     unsigned* __restrict__ g_t1,
                                                     float* __restrict__ out) {
    __shared__ __bf16 ldsA[2][TILE * LDW];
    __shared__ __bf16 ldsB[2][TILE * LDW];
    __shared__ float  sw[8];
    __shared__ bool   amLast;

    const int tid    = threadIdx.x;
    const int l      = tid & 63;
    const int lane15 = l & 15;
    const int quad   = l >> 4;
    const int w      = tid >> 6;               // wave 0..7
    const int wr     = (w & 3) * 32;           // wave rows: 32
    const int wc     = (w >> 2) * 64;          // wave cols: 64

    const int bi = blockIdx.x >> 6;            // row block [0,64)
    const int bj = blockIdx.x & 63;            // col block [0,64)

    // staging map (r13-verified 0 conflicts): thread t -> row r = t>>2, q = t&3,
    // 16 contiguous bf16 at k0+q*16 -> two b128 writes at q*16 and q*16+8
    const int r = tid >> 2;
    const int q = tid & 3;
    const __bf16* ga = zb + (size_t)(bi * TILE + r) * D + q * 16;
    const __bf16* gb = zb + (size_t)(bj * TILE + r) * D + q * 16;
    const int wofs = r * LDW + q * 16;

    bf16x8_t sa0, sa1, sb0, sb1;
    auto load_regs = [&](int c) {
        const int k0 = c * BK;
        sa0 = *(const bf16x8_t*)(ga + k0);
        sa1 = *(const bf16x8_t*)(ga + k0 + 8);
        sb0 = *(const bf16x8_t*)(gb + k0);
        sb1 = *(const bf16x8_t*)(gb + k0 + 8);
    };
    auto write_lds = [&](int buf) {
        *(bf16x8_t*)(&ldsA[buf][wofs])     = sa0;
        *(bf16x8_t*)(&ldsA[buf][wofs + 8]) = sa1;
        *(bf16x8_t*)(&ldsB[buf][wofs])     = sb0;
        *(bf16x8_t*)(&ldsB[buf][wofs + 8]) = sb1;
    };

    f32x4_t acc[2][4];
    #pragma unroll
    for (int mi = 0; mi < 2; ++mi)
        #pragma unroll
        for (int nj = 0; nj < 4; ++nj)
            acc[mi][nj] = (f32x4_t){0.f, 0.f, 0.f, 0.f};

    auto compute = [&](int buf) {
        #pragma unroll
        for (int ks = 0; ks < 2; ++ks) {
            bf16x8_t af[2], bff[4];
            #pragma unroll
            for (int mi = 0; mi < 2; ++mi)
                af[mi] = *(const bf16x8_t*)(&ldsA[buf][(wr + mi * 16 + lane15) * LDW + ks * 32 + quad * 8]);
            #pragma unroll
            for (int nj = 0; nj < 4; ++nj)
                bff[nj] = *(const bf16x8_t*)(&ldsB[buf][(wc + nj * 16 + lane15) * LDW + ks * 32 + quad * 8]);
            #pragma unroll
            for (int mi = 0; mi < 2; ++mi)
                #pragma unroll
                for (int nj = 0; nj < 4; ++nj)
                    acc[mi][nj] = __builtin_amdgcn_mfma_f32_16x16x32_bf16(bff[nj], af[mi], acc[mi][nj], 0, 0, 0);
        }
    };

    // prologue: stage chunk 0
    load_regs(0);
    write_lds(0);
    __syncthreads();

    int cur = 0;
    #pragma unroll
    for (int c = 0; c < NCH; ++c) {
        if (c + 1 < NCH) load_regs(c + 1);
        compute(cur);
        if (c + 1 < NCH) {
            write_lds(cur ^ 1);     // safe: buf[cur^1] readers all passed prior barrier
            __syncthreads();
            cur ^= 1;
        }
    }

    // epilogue: e = exp(sim/T) = exp2(acc * 2/ln2); zero self-similarity; row sums
    // acc[mi][nj]: S-row = bi*128+wr+mi*16+lane15, S-col = bj*128+wc+nj*16+quad*4+t
    float rs[2] = {0.f, 0.f};
    #pragma unroll
    for (int mi = 0; mi < 2; ++mi) {
        #pragma unroll
        for (int nj = 0; nj < 4; ++nj) {
            const bool dn = (bi == bj) && (wr + mi * 16 == wc + nj * 16);  // diag frag (wave-uniform)
            #pragma unroll
            for (int t = 0; t < 4; ++t) {
                float e = exp2f(acc[mi][nj][t] * 2.8853900817779268f);
                if (dn && (quad * 4 + t) == lane15) e = 0.0f;
                rs[mi] += e;
            }
        }
    }
    #pragma unroll
    for (int mi = 0; mi < 2; ++mi) {
        rs[mi] += __shfl_xor(rs[mi], 16, 64);
        rs[mi] += __shfl_xor(rs[mi], 32, 64);
    }
    if (l < 16) {
        #pragma unroll
        for (int mi = 0; mi < 2; ++mi)
            atomicAdd(&g_denom[bi * TILE + wr + mi * 16 + l], rs[mi]);
    }

    // ---------------- two-level fenceless ticket fin (r12-verified) ----------------
    __syncthreads();                 // drains vmcnt for every wave -> adds complete
    if (tid == 0) {
        asm volatile("s_waitcnt vmcnt(0)" ::: "memory");
        unsigned t1 = __hip_atomic_fetch_add(&g_t1[bi * 32], 1u, __ATOMIC_RELAXED,
                                             __HIP_MEMORY_SCOPE_AGENT);
        bool grpLast = (t1 == 63);
        unsigned t2 = 0;
        if (grpLast)
            t2 = __hip_atomic_fetch_add(&g_t1[64 * 32], 1u, __ATOMIC_RELAXED,
                                        __HIP_MEMORY_SCOPE_AGENT);
        amLast = grpLast && (t2 == 63);
    }
    __syncthreads();
    if (!amLast) return;

    float local = 0.0f;
    for (int k = tid; k < N2; k += TPB) {
        float dn = __hip_atomic_load(&g_denom[k], __ATOMIC_RELAXED,
                                     __HIP_MEMORY_SCOPE_AGENT);
        local += logf(dn) - 2.0f * g_pos[k];
    }
    #pragma unroll
    for (int off = 32; off; off >>= 1) local += __shfl_xor(local, off, 64);
    if (l == 0) sw[w] = local;
    __syncthreads();
    if (tid == 0) {
        float s = 0.f;
        #pragma unroll
        for (int i = 0; i < 8; ++i) s += sw[i];
        out[0] = s / (float)N2;
    }
}

extern "C" void kernel_launch(void* const* d_in, const int* in_sizes, int n_in,
                              void* d_out, int out_size, void* d_ws, size_t ws_size,
                              hipStream_t stream) {
    const float* emb_i = (const float*)d_in[0];
    const float* emb_j = (const float*)d_in[1];

    __bf16*   zb      = (__bf16*)d_ws;                                 // 4 MB
    float*    g_denom = (float*)((char*)d_ws + (size_t)N2 * D * 2);    // 8192 fp32
    float*    g_pos   = g_denom + N2;                                  // 8192 fp32
    unsigned* g_t1    = (unsigned*)(g_pos + N2);                       // 64*32+1 u32 tickets
    float*    out     = (float*)d_out;

    prep_kernel<<<NHALF / 4, 256, 0, stream>>>(emb_i, emb_j, zb, g_pos, g_denom, g_t1);
    sim_kernel<<<NBLK2, TPB, 0, stream>>>(zb, g_denom, g_pos, g_t1, out);
}

// Round 15
// 115.606 us; speedup vs baseline: 1.4196x; 1.0580x over previous
//
#include <hip/hip_runtime.h>
#include <hip/hip_bf16.h>
#include <math.h>

#define D      256
#define N2     8192
#define NHALF  4096
#define TILE   128
#define BK     64
#define NCH    4        // 256 / BK
#define LDW    68       // 136B row stride: read+write maps r5/r13/r14-verified 0-conflict
#define NTRI   2080     // 64*65/2 triangular tiles (bi <= bj)
#define TPB    512      // 8 waves/block, 2 blocks/CU (r12/r14-verified)

typedef __bf16 bf16x8_t __attribute__((ext_vector_type(8)));
typedef __bf16 bf16x4_t __attribute__((ext_vector_type(4)));
typedef float  f32x4_t  __attribute__((ext_vector_type(4)));

// ---------------- kernel 1: fused normalize + positives + denom/ticket zero --------
__global__ __launch_bounds__(256) void prep_kernel(const float* __restrict__ a,
                                                   const float* __restrict__ b,
                                                   __bf16* __restrict__ zb,
                                                   float* __restrict__ g_pos,
                                                   float* __restrict__ g_denom,
                                                   unsigned* __restrict__ g_t1) {
    const int tid = threadIdx.x;
    const int gt  = blockIdx.x * 256 + tid;
    if (gt < N2) g_denom[gt] = 0.0f;
    if (gt < 65 * 32 + 1) g_t1[gt] = 0u;       // 65 spaced L1 tickets + 1 L2 ticket

    const int w = blockIdx.x * 4 + (tid >> 6);  // pair row in [0, NHALF)
    const int l = tid & 63;
    float4 x = ((const float4*)(a + (size_t)w * D))[l];
    float4 y = ((const float4*)(b + (size_t)w * D))[l];
    float sxx = x.x * x.x + x.y * x.y + x.z * x.z + x.w * x.w;
    float syy = y.x * y.x + y.y * y.y + y.z * y.z + y.w * y.w;
    float sxy = x.x * y.x + x.y * y.y + x.z * y.z + x.w * y.w;
    #pragma unroll
    for (int off = 32; off; off >>= 1) {
        sxx += __shfl_xor(sxx, off, 64);
        syy += __shfl_xor(syy, off, 64);
        sxy += __shfl_xor(sxy, off, 64);
    }
    const float rx = 1.0f / fmaxf(sqrtf(sxx), 1e-8f);
    const float ry = 1.0f / fmaxf(sqrtf(syy), 1e-8f);

    bf16x4_t ox, oy;
    ox[0] = (__bf16)(x.x * rx); ox[1] = (__bf16)(x.y * rx);
    ox[2] = (__bf16)(x.z * rx); ox[3] = (__bf16)(x.w * rx);
    oy[0] = (__bf16)(y.x * ry); oy[1] = (__bf16)(y.y * ry);
    oy[2] = (__bf16)(y.z * ry); oy[3] = (__bf16)(y.w * ry);
    *(bf16x4_t*)(zb + (size_t)w * D + l * 4)           = ox;
    *(bf16x4_t*)(zb + (size_t)(w + NHALF) * D + l * 4) = oy;

    if (l == 0) {
        const float p = sxy * rx * ry;
        g_pos[w]         = p;
        g_pos[w + NHALF] = p;
    }
}

// ---------------- kernel 2: TRIANGULAR r14 sim (bi<=bj) + two-level ticket fin -----
// r14 closed the model: chunk-round 5140cyc = LDS pipe 3072 + MFMA 1242 + L2 1170,
// near-serialized; LDS instr count is invariant to occupancy/conflicts, so the only
// lever is WORK. sim is symmetric: compute only tiles bi<=bj (2080 blocks vs 4096).
// Inner loop/staging/LDS maps byte-identical to r14 (verified 0-conflict). Off-diag
// tiles add each exp'd element to BOTH its row sum (bi panel) and a column
// accumulator; column sums (= row sums of panel bj, by symmetry) are reduced over
// lane15 with 4 shfl_xor steps ONCE PER TILE (r0's fatal cost was per-16-col-strip)
// and atomicAdd'ed to g_denom[bj*128+col]. Diag tiles: r14 epilogue unchanged.
// Halves MFMA, LDS traffic, staging, exp. Ticket: 2080 = 65x32 exactly.
__global__ __launch_bounds__(TPB, 4) void sim_kernel(const __bf16* __restrict__ zb,
                                                     float* __restrict__ g_denom,
                                                     const float* __restrict__ g_pos,
                                                     unsigned* __restrict__ g_t1,
                                                     float* __restrict__ out) {
    __shared__ __bf16 ldsA[2][TILE * LDW];
    __shared__ __bf16 ldsB[2][TILE * LDW];
    __shared__ float  sw[8];
    __shared__ bool   amLast;

    const int tid    = threadIdx.x;
    const int l      = tid & 63;
    const int lane15 = l & 15;
    const int quad   = l >> 4;
    const int w      = tid >> 6;               // wave 0..7
    const int wr     = (w & 3) * 32;           // wave rows: 32
    const int wc     = (w >> 2) * 64;          // wave cols: 64

    // triangular decode: k -> (bi, bj), bi <= bj; off(bi) = bi*(129-bi)/2
    const int k = blockIdx.x;
    int bi = (int)(64.5f - sqrtf(64.5f * 64.5f - 2.0f * (float)k));
    while ((bi * (129 - bi)) / 2 > k) --bi;
    while (((bi + 1) * (128 - bi)) / 2 <= k) ++bi;
    const int bj   = bi + (k - (bi * (129 - bi)) / 2);
    const bool diag = (bi == bj);

    // staging map (r13/r14-verified 0 conflicts): row r = t>>2, q = t&3, 16 bf16 at q*16
    const int r = tid >> 2;
    const int q = tid & 3;
    const __bf16* ga = zb + (size_t)(bi * TILE + r) * D + q * 16;
    const __bf16* gb = zb + (size_t)(bj * TILE + r) * D + q * 16;
    const int wofs = r * LDW + q * 16;

    bf16x8_t sa0, sa1, sb0, sb1;
    auto load_regs = [&](int c) {
        const int k0 = c * BK;
        sa0 = *(const bf16x8_t*)(ga + k0);
        sa1 = *(const bf16x8_t*)(ga + k0 + 8);
        sb0 = *(const bf16x8_t*)(gb + k0);
        sb1 = *(const bf16x8_t*)(gb + k0 + 8);
    };
    auto write_lds = [&](int buf) {
        *(bf16x8_t*)(&ldsA[buf][wofs])     = sa0;
        *(bf16x8_t*)(&ldsA[buf][wofs + 8]) = sa1;
        *(bf16x8_t*)(&ldsB[buf][wofs])     = sb0;
        *(bf16x8_t*)(&ldsB[buf][wofs + 8]) = sb1;
    };

    f32x4_t acc[2][4];
    #pragma unroll
    for (int mi = 0; mi < 2; ++mi)
        #pragma unroll
        for (int nj = 0; nj < 4; ++nj)
            acc[mi][nj] = (f32x4_t){0.f, 0.f, 0.f, 0.f};

    auto compute = [&](int buf) {
        #pragma unroll
        for (int ks = 0; ks < 2; ++ks) {
            bf16x8_t af[2], bff[4];
            #pragma unroll
            for (int mi = 0; mi < 2; ++mi)
                af[mi] = *(const bf16x8_t*)(&ldsA[buf][(wr + mi * 16 + lane15) * LDW + ks * 32 + quad * 8]);
            #pragma unroll
            for (int nj = 0; nj < 4; ++nj)
                bff[nj] = *(const bf16x8_t*)(&ldsB[buf][(wc + nj * 16 + lane15) * LDW + ks * 32 + quad * 8]);
            #pragma unroll
            for (int mi = 0; mi < 2; ++mi)
                #pragma unroll
                for (int nj = 0; nj < 4; ++nj)
                    acc[mi][nj] = __builtin_amdgcn_mfma_f32_16x16x32_bf16(bff[nj], af[mi], acc[mi][nj], 0, 0, 0);
        }
    };

    // prologue: stage chunk 0
    load_regs(0);
    write_lds(0);
    __syncthreads();

    int cur = 0;
    #pragma unroll
    for (int c = 0; c < NCH; ++c) {
        if (c + 1 < NCH) load_regs(c + 1);
        compute(cur);
        if (c + 1 < NCH) {
            write_lds(cur ^ 1);     // safe: buf[cur^1] readers all passed prior barrier
            __syncthreads();
            cur ^= 1;
        }
    }

    // epilogue: e = exp2(acc * 2/ln2); rows -> bi panel; cols (off-diag) -> bj panel
    // acc[mi][nj]: S-row = bi*128+wr+mi*16+lane15, S-col = bj*128+wc+nj*16+quad*4+t
    float rs[2] = {0.f, 0.f};
    float cp[4][4];
    #pragma unroll
    for (int nj = 0; nj < 4; ++nj)
        #pragma unroll
        for (int t = 0; t < 4; ++t) cp[nj][t] = 0.f;

    #pragma unroll
    for (int mi = 0; mi < 2; ++mi) {
        #pragma unroll
        for (int nj = 0; nj < 4; ++nj) {
            const bool dn = diag && (wr + mi * 16 == wc + nj * 16);   // wave-uniform
            #pragma unroll
            for (int t = 0; t < 4; ++t) {
                float e = exp2f(acc[mi][nj][t] * 2.8853900817779268f);
                if (dn && (quad * 4 + t) == lane15) e = 0.0f;
                rs[mi] += e;
                cp[nj][t] += e;                   // only consumed when !diag
            }
        }
    }
    // row sums: reduce 4 quads sharing each row, one atomic per row
    #pragma unroll
    for (int mi = 0; mi < 2; ++mi) {
        rs[mi] += __shfl_xor(rs[mi], 16, 64);
        rs[mi] += __shfl_xor(rs[mi], 32, 64);
    }
    if (l < 16) {
        #pragma unroll
        for (int mi = 0; mi < 2; ++mi)
            atomicAdd(&g_denom[bi * TILE + wr + mi * 16 + l], rs[mi]);
    }
    // column sums (once per tile): reduce over lane15 (rows), add to bj panel rows
    if (!diag) {
        #pragma unroll
        for (int nj = 0; nj < 4; ++nj)
            #pragma unroll
            for (int t = 0; t < 4; ++t) {
                cp[nj][t] += __shfl_xor(cp[nj][t], 1, 64);
                cp[nj][t] += __shfl_xor(cp[nj][t], 2, 64);
                cp[nj][t] += __shfl_xor(cp[nj][t], 4, 64);
                cp[nj][t] += __shfl_xor(cp[nj][t], 8, 64);
            }
        if (lane15 == 0) {
            #pragma unroll
            for (int nj = 0; nj < 4; ++nj)
                #pragma unroll
                for (int t = 0; t < 4; ++t)
                    atomicAdd(&g_denom[bj * TILE + wc + nj * 16 + quad * 4 + t], cp[nj][t]);
        }
    }

    // ---------------- two-level fenceless ticket fin (65 groups x 32) ----------------
    __syncthreads();                 // drains vmcnt for every wave -> adds complete
    if (tid == 0) {
        asm volatile("s_waitcnt vmcnt(0)" ::: "memory");
        unsigned t1 = __hip_atomic_fetch_add(&g_t1[(blockIdx.x >> 5) * 32], 1u,
                                             __ATOMIC_RELAXED, __HIP_MEMORY_SCOPE_AGENT);
        bool grpLast = (t1 == 31);
        unsigned t2 = 0;
        if (grpLast)
            t2 = __hip_atomic_fetch_add(&g_t1[65 * 32], 1u, __ATOMIC_RELAXED,
                                        __HIP_MEMORY_SCOPE_AGENT);
        amLast = grpLast && (t2 == 64);
    }
    __syncthreads();
    if (!amLast) return;

    float local = 0.0f;
    for (int kk = tid; kk < N2; kk += TPB) {
        float dn = __hip_atomic_load(&g_denom[kk], __ATOMIC_RELAXED,
                                     __HIP_MEMORY_SCOPE_AGENT);
        local += logf(dn) - 2.0f * g_pos[kk];
    }
    #pragma unroll
    for (int off = 32; off; off >>= 1) local += __shfl_xor(local, off, 64);
    if (l == 0) sw[w] = local;
    __syncthreads();
    if (tid == 0) {
        float s = 0.f;
        #pragma unroll
        for (int i = 0; i < 8; ++i) s += sw[i];
        out[0] = s / (float)N2;
    }
}

extern "C" void kernel_launch(void* const* d_in, const int* in_sizes, int n_in,
                              void* d_out, int out_size, void* d_ws, size_t ws_size,
                              hipStream_t stream) {
    const float* emb_i = (const float*)d_in[0];
    const float* emb_j = (const float*)d_in[1];

    __bf16*   zb      = (__bf16*)d_ws;                                 // 4 MB
    float*    g_denom = (float*)((char*)d_ws + (size_t)N2 * D * 2);    // 8192 fp32
    float*    g_pos   = g_denom + N2;                                  // 8192 fp32
    unsigned* g_t1    = (unsigned*)(g_pos + N2);                       // 65*32+1 u32 tickets
    float*    out     = (float*)d_out;

    prep_kernel<<<NHALF / 4, 256, 0, stream>>>(emb_i, emb_j, zb, g_pos, g_denom, g_t1);
    sim_kernel<<<NTRI, TPB, 0, stream>>>(zb, g_denom, g_pos, g_t1, out);
}

// Round 16
// 100.811 us; speedup vs baseline: 1.6279x; 1.1468x over previous
//
#include <hip/hip_runtime.h>
#include <hip/hip_bf16.h>
#include <math.h>

#define D      256
#define N2     8192
#define NHALF  4096
#define TILE   128
#define BK     64
#define NCH    4        // 256 / BK
#define LDW    68       // 136B row stride: read+write maps r5/r13/r14-verified 0-conflict
#define NTRI   2080     // 64*65/2 triangular tiles (bi <= bj)
#define TPB    512      // 8 waves/block, 2 blocks/CU (r12/r14-verified)

typedef __bf16 bf16x8_t __attribute__((ext_vector_type(8)));
typedef __bf16 bf16x4_t __attribute__((ext_vector_type(4)));
typedef float  f32x4_t  __attribute__((ext_vector_type(4)));

// ---------------- kernel 1: fused normalize + positives + denom/ticket zero --------
__global__ __launch_bounds__(256) void prep_kernel(const float* __restrict__ a,
                                                   const float* __restrict__ b,
                                                   __bf16* __restrict__ zb,
                                                   float* __restrict__ g_pos,
                                                   float* __restrict__ g_denom,
                                                   unsigned* __restrict__ g_t1) {
    const int tid = threadIdx.x;
    const int gt  = blockIdx.x * 256 + tid;
    if (gt < N2) g_denom[gt] = 0.0f;
    if (gt < 65 * 32 + 1) g_t1[gt] = 0u;       // 65 spaced L1 tickets + 1 L2 ticket

    const int w = blockIdx.x * 4 + (tid >> 6);  // pair row in [0, NHALF)
    const int l = tid & 63;
    float4 x = ((const float4*)(a + (size_t)w * D))[l];
    float4 y = ((const float4*)(b + (size_t)w * D))[l];
    float sxx = x.x * x.x + x.y * x.y + x.z * x.z + x.w * x.w;
    float syy = y.x * y.x + y.y * y.y + y.z * y.z + y.w * y.w;
    float sxy = x.x * y.x + x.y * y.y + x.z * y.z + x.w * y.w;
    #pragma unroll
    for (int off = 32; off; off >>= 1) {
        sxx += __shfl_xor(sxx, off, 64);
        syy += __shfl_xor(syy, off, 64);
        sxy += __shfl_xor(sxy, off, 64);
    }
    const float rx = 1.0f / fmaxf(sqrtf(sxx), 1e-8f);
    const float ry = 1.0f / fmaxf(sqrtf(syy), 1e-8f);

    bf16x4_t ox, oy;
    ox[0] = (__bf16)(x.x * rx); ox[1] = (__bf16)(x.y * rx);
    ox[2] = (__bf16)(x.z * rx); ox[3] = (__bf16)(x.w * rx);
    oy[0] = (__bf16)(y.x * ry); oy[1] = (__bf16)(y.y * ry);
    oy[2] = (__bf16)(y.z * ry); oy[3] = (__bf16)(y.w * ry);
    *(bf16x4_t*)(zb + (size_t)w * D + l * 4)           = ox;
    *(bf16x4_t*)(zb + (size_t)(w + NHALF) * D + l * 4) = oy;

    if (l == 0) {
        const float p = sxy * rx * ry;
        g_pos[w]         = p;
        g_pos[w + NHALF] = p;
    }
}

// ---------------- kernel 2: triangular sim + recursive-halving col reduce ----------
// r15 post-mortem: triangle halved the work but per-tile time grew 1.75x -- the
// column epilogue's 64 shfl_xor (LDS-pipe ops, on the bottleneck pipe, 4-deep
// chains) + 16 serialized atomic instrs ate ~half the savings. This round, single
// change: recursive-halving distribute-reduce -- stage d in {8,4,2,1}: each lane
// sends the half of its live values the partner owns, keeps+adds the rest. 15 shfl
// + 15 adds (vs 64+64), and the result is DISTRIBUTED: lane l15 ends with the col
// sum for v=l15 -> ONE 64-lane atomicAdd instruction (64 distinct addresses) vs 16
// serialized. Main loop/staging byte-identical to r15 (0-conflict verified).
__global__ __launch_bounds__(TPB, 4) void sim_kernel(const __bf16* __restrict__ zb,
                                                     float* __restrict__ g_denom,
                                                     const float* __restrict__ g_pos,
                                                     unsigned* __restrict__ g_t1,
                                                     float* __restrict__ out) {
    __shared__ __bf16 ldsA[2][TILE * LDW];
    __shared__ __bf16 ldsB[2][TILE * LDW];
    __shared__ float  sw[8];
    __shared__ bool   amLast;

    const int tid    = threadIdx.x;
    const int l      = tid & 63;
    const int lane15 = l & 15;
    const int quad   = l >> 4;
    const int w      = tid >> 6;               // wave 0..7
    const int wr     = (w & 3) * 32;           // wave rows: 32
    const int wc     = (w >> 2) * 64;          // wave cols: 64

    // triangular decode: k -> (bi, bj), bi <= bj; off(bi) = bi*(129-bi)/2
    const int k = blockIdx.x;
    int bi = (int)(64.5f - sqrtf(64.5f * 64.5f - 2.0f * (float)k));
    while ((bi * (129 - bi)) / 2 > k) --bi;
    while (((bi + 1) * (128 - bi)) / 2 <= k) ++bi;
    const int bj   = bi + (k - (bi * (129 - bi)) / 2);
    const bool diag = (bi == bj);

    // staging map (r13/r14-verified 0 conflicts): row r = t>>2, q = t&3, 16 bf16 at q*16
    const int r = tid >> 2;
    const int q = tid & 3;
    const __bf16* ga = zb + (size_t)(bi * TILE + r) * D + q * 16;
    const __bf16* gb = zb + (size_t)(bj * TILE + r) * D + q * 16;
    const int wofs = r * LDW + q * 16;

    bf16x8_t sa0, sa1, sb0, sb1;
    auto load_regs = [&](int c) {
        const int k0 = c * BK;
        sa0 = *(const bf16x8_t*)(ga + k0);
        sa1 = *(const bf16x8_t*)(ga + k0 + 8);
        sb0 = *(const bf16x8_t*)(gb + k0);
        sb1 = *(const bf16x8_t*)(gb + k0 + 8);
    };
    auto write_lds = [&](int buf) {
        *(bf16x8_t*)(&ldsA[buf][wofs])     = sa0;
        *(bf16x8_t*)(&ldsA[buf][wofs + 8]) = sa1;
        *(bf16x8_t*)(&ldsB[buf][wofs])     = sb0;
        *(bf16x8_t*)(&ldsB[buf][wofs + 8]) = sb1;
    };

    f32x4_t acc[2][4];
    #pragma unroll
    for (int mi = 0; mi < 2; ++mi)
        #pragma unroll
        for (int nj = 0; nj < 4; ++nj)
            acc[mi][nj] = (f32x4_t){0.f, 0.f, 0.f, 0.f};

    auto compute = [&](int buf) {
        #pragma unroll
        for (int ks = 0; ks < 2; ++ks) {
            bf16x8_t af[2], bff[4];
            #pragma unroll
            for (int mi = 0; mi < 2; ++mi)
                af[mi] = *(const bf16x8_t*)(&ldsA[buf][(wr + mi * 16 + lane15) * LDW + ks * 32 + quad * 8]);
            #pragma unroll
            for (int nj = 0; nj < 4; ++nj)
                bff[nj] = *(const bf16x8_t*)(&ldsB[buf][(wc + nj * 16 + lane15) * LDW + ks * 32 + quad * 8]);
            #pragma unroll
            for (int mi = 0; mi < 2; ++mi)
                #pragma unroll
                for (int nj = 0; nj < 4; ++nj)
                    acc[mi][nj] = __builtin_amdgcn_mfma_f32_16x16x32_bf16(bff[nj], af[mi], acc[mi][nj], 0, 0, 0);
        }
    };

    // prologue: stage chunk 0
    load_regs(0);
    write_lds(0);
    __syncthreads();

    int cur = 0;
    #pragma unroll
    for (int c = 0; c < NCH; ++c) {
        if (c + 1 < NCH) load_regs(c + 1);
        compute(cur);
        if (c + 1 < NCH) {
            write_lds(cur ^ 1);     // safe: buf[cur^1] readers all passed prior barrier
            __syncthreads();
            cur ^= 1;
        }
    }

    // epilogue: e = exp2(acc * 2/ln2); rows -> bi panel; cols (off-diag) -> bj panel
    // acc[mi][nj]: S-row = bi*128+wr+mi*16+lane15, S-col = bj*128+wc+nj*16+quad*4+t
    float rs[2] = {0.f, 0.f};
    float cp[4][4];
    #pragma unroll
    for (int nj = 0; nj < 4; ++nj)
        #pragma unroll
        for (int t = 0; t < 4; ++t) cp[nj][t] = 0.f;

    #pragma unroll
    for (int mi = 0; mi < 2; ++mi) {
        #pragma unroll
        for (int nj = 0; nj < 4; ++nj) {
            const bool dn = diag && (wr + mi * 16 == wc + nj * 16);   // wave-uniform
            #pragma unroll
            for (int t = 0; t < 4; ++t) {
                float e = exp2f(acc[mi][nj][t] * 2.8853900817779268f);
                if (dn && (quad * 4 + t) == lane15) e = 0.0f;
                rs[mi] += e;
                cp[nj][t] += e;                   // only consumed when !diag
            }
        }
    }
    // row sums: reduce 4 quads sharing each row, one atomic per row
    #pragma unroll
    for (int mi = 0; mi < 2; ++mi) {
        rs[mi] += __shfl_xor(rs[mi], 16, 64);
        rs[mi] += __shfl_xor(rs[mi], 32, 64);
    }
    if (l < 16) {
        #pragma unroll
        for (int mi = 0; mi < 2; ++mi)
            atomicAdd(&g_denom[bi * TILE + wr + mi * 16 + l], rs[mi]);
    }
    // column sums via recursive halving: 15 shfl, result distributed (lane15 = v),
    // then ONE 64-lane atomicAdd (columns all distinct: quad*4 + value layout).
    if (!diag) {
        float s8[8], s4[4], s2[2], s;
        #pragma unroll
        for (int i = 0; i < 8; ++i) {
            const float lo = cp[i >> 2][i & 3];
            const float hi = cp[(i + 8) >> 2][(i + 8) & 3];
            const float send = (lane15 & 8) ? lo : hi;
            const float recv = __shfl_xor(send, 8, 64);
            s8[i] = ((lane15 & 8) ? hi : lo) + recv;     // v = i + (lane15 & 8)
        }
        #pragma unroll
        for (int i = 0; i < 4; ++i) {
            const float send = (lane15 & 4) ? s8[i] : s8[i + 4];
            const float recv = __shfl_xor(send, 4, 64);
            s4[i] = ((lane15 & 4) ? s8[i + 4] : s8[i]) + recv;   // v += (lane15 & 4)
        }
        #pragma unroll
        for (int i = 0; i < 2; ++i) {
            const float send = (lane15 & 2) ? s4[i] : s4[i + 2];
            const float recv = __shfl_xor(send, 2, 64);
            s2[i] = ((lane15 & 2) ? s4[i + 2] : s4[i]) + recv;   // v += (lane15 & 2)
        }
        {
            const float send = (lane15 & 1) ? s2[0] : s2[1];
            const float recv = __shfl_xor(send, 1, 64);
            s = ((lane15 & 1) ? s2[1] : s2[0]) + recv;           // v = lane15
        }
        atomicAdd(&g_denom[bj * TILE + wc + (lane15 >> 2) * 16 + quad * 4 + (lane15 & 3)], s);
    }

    // ---------------- two-level fenceless ticket fin (65 groups x 32) ----------------
    __syncthreads();                 // drains vmcnt for every wave -> adds complete
    if (tid == 0) {
        asm volatile("s_waitcnt vmcnt(0)" ::: "memory");
        unsigned t1 = __hip_atomic_fetch_add(&g_t1[(blockIdx.x >> 5) * 32], 1u,
                                             __ATOMIC_RELAXED, __HIP_MEMORY_SCOPE_AGENT);
        bool grpLast = (t1 == 31);
        unsigned t2 = 0;
        if (grpLast)
            t2 = __hip_atomic_fetch_add(&g_t1[65 * 32], 1u, __ATOMIC_RELAXED,
                                        __HIP_MEMORY_SCOPE_AGENT);
        amLast = grpLast && (t2 == 64);
    }
    __syncthreads();
    if (!amLast) return;

    float local = 0.0f;
    for (int kk = tid; kk < N2; kk += TPB) {
        float dn = __hip_atomic_load(&g_denom[kk], __ATOMIC_RELAXED,
                                     __HIP_MEMORY_SCOPE_AGENT);
        local += logf(dn) - 2.0f * g_pos[kk];
    }
    #pragma unroll
    for (int off = 32; off; off >>= 1) local += __shfl_xor(local, off, 64);
    if (l == 0) sw[w] = local;
    __syncthreads();
    if (tid == 0) {
        float s = 0.f;
        #pragma unroll
        for (int i = 0; i < 8; ++i) s += sw[i];
        out[0] = s / (float)N2;
    }
}

extern "C" void kernel_launch(void* const* d_in, const int* in_sizes, int n_in,
                              void* d_out, int out_size, void* d_ws, size_t ws_size,
                              hipStream_t stream) {
    const float* emb_i = (const float*)d_in[0];
    const float* emb_j = (const float*)d_in[1];

    __bf16*   zb      = (__bf16*)d_ws;                                 // 4 MB
    float*    g_denom = (float*)((char*)d_ws + (size_t)N2 * D * 2);    // 8192 fp32
    float*    g_pos   = g_denom + N2;                                  // 8192 fp32
    unsigned* g_t1    = (unsigned*)(g_pos + N2);                       // 65*32+1 u32 tickets
    float*    out     = (float*)d_out;

    prep_kernel<<<NHALF / 4, 256, 0, stream>>>(emb_i, emb_j, zb, g_pos, g_denom, g_t1);
    sim_kernel<<<NTRI, TPB, 0, stream>>>(zb, g_denom, g_pos, g_t1, out);
}